// Round 1
// baseline (767.800 us; speedup 1.0000x reference)
//
#include <hip/hip_runtime.h>
#include <hip/hip_bf16.h>

// Sizes (fixed by problem)
#define EE  131072   // edges
#define BB  64       // graphs
#define HH  256      // hidden
#define SS  32       // seeds
#define NHD 8        // heads
#define HDD 32       // head dim
#define NCC 256      // S*NH seed-head columns

typedef _Float16 f16;
typedef _Float16 f16x4 __attribute__((ext_vector_type(4)));
typedef float    f32x4 __attribute__((ext_vector_type(4)));
typedef unsigned short u16x8 __attribute__((ext_vector_type(8)));

static __device__ __forceinline__ unsigned short f2h(float x){
  f16 h = (f16)x; unsigned short u; __builtin_memcpy(&u, &h, 2); return u;
}
static __device__ __forceinline__ float h2f(unsigned short u){
  f16 h; __builtin_memcpy(&h, &u, 2); return (float)h;
}
static __device__ __forceinline__ unsigned int pk2(float a, float b){
  return (unsigned int)f2h(a) | ((unsigned int)f2h(b) << 16);
}

// ---------------- K0: segment offsets from sorted batch ----------------
__global__ __launch_bounds__(256) void k_seg(const int* __restrict__ batch, int* __restrict__ seg){
  int e = blockIdx.x * 256 + threadIdx.x;
  if (e == 0){ seg[0] = 0; seg[BB] = EE; }
  if (e > 0 && e < EE){
    int b = batch[e];
    if (batch[e-1] != b) seg[b] = e;
  }
}

// ---------------- K1a: q = seeds @ w_q ----------------
__global__ __launch_bounds__(256) void k_qproj(const float* __restrict__ seeds,
                                               const float* __restrict__ wq,
                                               float* __restrict__ qf){
  __shared__ float ssh[HH];
  int s = blockIdx.x, t = threadIdx.x;
  ssh[t] = seeds[s*HH + t];
  __syncthreads();
  float acc = 0.f;
  for (int j = 0; j < HH; j++) acc += ssh[j] * wq[j*HH + t];
  qf[s*HH + t] = acc;
}

// ---------------- K1b: WsC[c][j] = (1/sqrt(32)) * sum_d w_k[j][h*32+d]*q[s][h*32+d] ----------------
__global__ __launch_bounds__(256) void k_wsc(const float* __restrict__ qf,
                                             const float* __restrict__ wk,
                                             f16* __restrict__ wsc){
  int c = blockIdx.x, t = threadIdx.x;
  int s = c >> 3, h = c & 7;
  __shared__ float qsh[HDD];
  if (t < HDD) qsh[t] = qf[s*HH + h*HDD + t];
  __syncthreads();
  const float* wrow = wk + (size_t)t*HH + h*HDD;
  float acc = 0.f;
#pragma unroll
  for (int d = 0; d < HDD; d++) acc += qsh[d] * wrow[d];
  wsc[c*HH + t] = (f16)(acc * 0.17677669529663687f);  // 1/sqrt(32)
}

// ---------------- K2: Xt[j][e] = f16(X[e][j])  (256 x E, edge-contiguous) ----------------
__global__ __launch_bounds__(256) void k_xt(const float* __restrict__ X, f16* __restrict__ Xt){
  int e0 = blockIdx.x * 64;
  int t = threadIdx.x;
  f16* dst = Xt + (size_t)t*EE + e0;
#pragma unroll
  for (int w = 0; w < 8; w++){
    unsigned int u0 = pk2(X[(size_t)(e0 + w*8 + 0)*HH + t], X[(size_t)(e0 + w*8 + 1)*HH + t]);
    unsigned int u1 = pk2(X[(size_t)(e0 + w*8 + 2)*HH + t], X[(size_t)(e0 + w*8 + 3)*HH + t]);
    unsigned int u2 = pk2(X[(size_t)(e0 + w*8 + 4)*HH + t], X[(size_t)(e0 + w*8 + 5)*HH + t]);
    unsigned int u3 = pk2(X[(size_t)(e0 + w*8 + 6)*HH + t], X[(size_t)(e0 + w*8 + 7)*HH + t]);
    *(uint4*)(dst + w*8) = make_uint4(u0, u1, u2, u3);
  }
}

// ---------------- K3: GEMM1  St = WsC (256x256) x X^T (256xE), fused exp + Pt write + denom ----------------
// Block: 512 thr (8 waves, 4m x 2n), tile M=256(c) x N=128(e), BK=64, mfma 16x16x16_f16
__global__ __launch_bounds__(512) void k_gemm1(const f16* __restrict__ wsc,
                                               const float* __restrict__ X,
                                               const int* __restrict__ batch,
                                               f16* __restrict__ Pt,
                                               float* __restrict__ denom){
  __shared__ __align__(16) unsigned char smem[66048];
  int* bsh = (int*)(smem + 65536);
  const int tid = threadIdx.x;
  const int e0 = blockIdx.x * 128;
  if (tid < 128) bsh[tid] = batch[e0 + tid];

  const int lane = tid & 63, wid = tid >> 6;
  const int wm = wid >> 1, wn = wid & 1;   // 4 x 2 wave grid, wave tile 64x64
  const int r16 = lane & 15, g = lane >> 4;

  f32x4 acc[4][4];
#pragma unroll
  for (int i = 0; i < 4; i++)
#pragma unroll
    for (int j = 0; j < 4; j++) acc[i][j] = (f32x4){0.f, 0.f, 0.f, 0.f};

  for (int j0 = 0; j0 < HH; j0 += 64){
    // stage A: WsC[0..256)[j0..j0+64) -> smem[0..32768), swizzled
#pragma unroll
    for (int it = 0; it < 4; it++){
      int idx = tid + it*512;
      int row = idx >> 3, ch = idx & 7;
      uint4 v = *(const uint4*)(wsc + row*HH + j0 + ch*8);
      *(uint4*)(smem + row*128 + ((ch*16) ^ ((row & 7) << 4))) = v;
    }
    // stage B: X[e0..e0+128)[j0..j0+64) f32 -> f16, smem[32768..49152), swizzled
#pragma unroll
    for (int it = 0; it < 2; it++){
      int idx = tid + it*512;
      int er = idx >> 3, ch = idx & 7;
      const float* src = X + (size_t)(e0 + er)*HH + j0 + ch*8;
      float4 f0 = *(const float4*)src;
      float4 f1 = *(const float4*)(src + 4);
      uint4 hv = make_uint4(pk2(f0.x, f0.y), pk2(f0.z, f0.w), pk2(f1.x, f1.y), pk2(f1.z, f1.w));
      *(uint4*)(smem + 32768 + er*128 + ((ch*16) ^ ((er & 7) << 4))) = hv;
    }
    __syncthreads();
#pragma unroll
    for (int ks = 0; ks < 4; ks++){
      const int kb2 = (ks*16 + g*4) * 2;   // byte offset within 128B row
      f16x4 af[4], bf[4];
#pragma unroll
      for (int mi = 0; mi < 4; mi++){
        int row = wm*64 + mi*16 + r16;
        af[mi] = *(const f16x4*)(smem + row*128 + (kb2 ^ ((row & 7) << 4)));
      }
#pragma unroll
      for (int ni = 0; ni < 4; ni++){
        int row = wn*64 + ni*16 + r16;
        bf[ni] = *(const f16x4*)(smem + 32768 + row*128 + (kb2 ^ ((row & 7) << 4)));
      }
#pragma unroll
      for (int mi = 0; mi < 4; mi++)
#pragma unroll
        for (int ni = 0; ni < 4; ni++)
          acc[mi][ni] = __builtin_amdgcn_mfma_f32_16x16x16f16(af[mi], bf[ni], acc[mi][ni], 0, 0, 0);
    }
    __syncthreads();
  }

  // epilogue: scores -> smem (f16, 16B-granule swizzle), then exp + Pt + denom
#pragma unroll
  for (int mi = 0; mi < 4; mi++)
#pragma unroll
    for (int ni = 0; ni < 4; ni++)
#pragma unroll
      for (int r = 0; r < 4; r++){
        int row = wm*64 + mi*16 + g*4 + r;   // c
        int col = wn*64 + ni*16 + r16;       // e-local
        *(unsigned short*)(smem + row*256 + ((col*2) ^ ((row & 7) << 4))) = f2h(acc[mi][ni][r]);
      }
  __syncthreads();

  const int rowc = tid >> 1, half = tid & 1;
  float dsum = 0.f;
  int curb = bsh[half*64];
#pragma unroll
  for (int ch = 0; ch < 8; ch++){
    int ebase = half*64 + ch*8;
    uint4 v = *(const uint4*)(smem + rowc*256 + ((half*128 + ch*16) ^ ((rowc & 7) << 4)));
    u16x8 hv; __builtin_memcpy(&hv, &v, 16);
    float p[8];
#pragma unroll
    for (int i = 0; i < 8; i++){
      p[i] = __expf(h2f(hv[i]) - 4.0f);   // constant shift; cancels in normalization
      int b = bsh[ebase + i];
      if (b != curb){ atomicAdd(&denom[curb*NCC + rowc], dsum); dsum = 0.f; curb = b; }
      dsum += p[i];
    }
    uint4 o = make_uint4(pk2(p[0], p[1]), pk2(p[2], p[3]), pk2(p[4], p[5]), pk2(p[6], p[7]));
    *(uint4*)(Pt + (size_t)rowc*EE + e0 + ebase) = o;
  }
  atomicAdd(&denom[curb*NCC + rowc], dsum);
}

// ---------------- K4: GEMM2  T[b] = P_b^T (256 x E_b) x X_b (E_b x 256) ----------------
// Block: 512 thr (8 waves, 2m x 4n), tile 128(c) x 128(j), K over segment edges
__global__ __launch_bounds__(512) void k_gemm2(const f16* __restrict__ Pt,
                                               const f16* __restrict__ Xt,
                                               const int* __restrict__ seg,
                                               float* __restrict__ T){
  __shared__ __align__(16) unsigned char smem[32768];
  const int b  = blockIdx.x >> 2;
  const int c0 = ((blockIdx.x >> 1) & 1) * 128;
  const int j0 = (blockIdx.x & 1) * 128;
  const int beg = seg[b], end = seg[b + 1];
  const int kbeg = beg & ~63;
  const int nsteps = (end - kbeg + 63) >> 6;

  const int tid = threadIdx.x;
  const int lane = tid & 63, wid = tid >> 6;
  const int wm = wid >> 2, wn = wid & 3;   // wave tile 64(c) x 32(j)
  const int r16 = lane & 15, g = lane >> 4;

  f32x4 acc[4][2];
#pragma unroll
  for (int i = 0; i < 4; i++)
#pragma unroll
    for (int j = 0; j < 2; j++) acc[i][j] = (f32x4){0.f, 0.f, 0.f, 0.f};

  for (int st = 0; st < nsteps; st++){
    int kk = kbeg + st*64;
    // stage A: Pt rows c0..c0+128, edges kk..kk+64, mask outside [beg,end)
#pragma unroll
    for (int it = 0; it < 2; it++){
      int idx = tid + it*512;
      int cr = idx >> 3, ch = idx & 7;
      int eb = kk + ch*8;
      uint4 v = *(const uint4*)(Pt + (size_t)(c0 + cr)*EE + eb);
      if (eb < beg || eb + 8 > end){
        u16x8 hv; __builtin_memcpy(&hv, &v, 16);
#pragma unroll
        for (int i = 0; i < 8; i++) if (eb + i < beg || eb + i >= end) hv[i] = (unsigned short)0;
        __builtin_memcpy(&v, &hv, 16);
      }
      *(uint4*)(smem + cr*128 + ((ch*16) ^ ((cr & 7) << 4))) = v;
    }
    // stage B: Xt rows j0..j0+128 (no mask needed; A is zeroed outside segment)
#pragma unroll
    for (int it = 0; it < 2; it++){
      int idx = tid + it*512;
      int jr = idx >> 3, ch = idx & 7;
      uint4 v = *(const uint4*)(Xt + (size_t)(j0 + jr)*EE + kk + ch*8);
      *(uint4*)(smem + 16384 + jr*128 + ((ch*16) ^ ((jr & 7) << 4))) = v;
    }
    __syncthreads();
#pragma unroll
    for (int ks = 0; ks < 4; ks++){
      const int kb2 = (ks*16 + g*4) * 2;
      f16x4 af[4], bf[2];
#pragma unroll
      for (int mi = 0; mi < 4; mi++){
        int row = wm*64 + mi*16 + r16;
        af[mi] = *(const f16x4*)(smem + row*128 + (kb2 ^ ((row & 7) << 4)));
      }
#pragma unroll
      for (int ni = 0; ni < 2; ni++){
        int row = wn*32 + ni*16 + r16;
        bf[ni] = *(const f16x4*)(smem + 16384 + row*128 + (kb2 ^ ((row & 7) << 4)));
      }
#pragma unroll
      for (int mi = 0; mi < 4; mi++)
#pragma unroll
        for (int ni = 0; ni < 2; ni++)
          acc[mi][ni] = __builtin_amdgcn_mfma_f32_16x16x16f16(af[mi], bf[ni], acc[mi][ni], 0, 0, 0);
    }
    __syncthreads();
  }

  float* Tb = T + (size_t)b*NCC*HH;
#pragma unroll
  for (int mi = 0; mi < 4; mi++)
#pragma unroll
    for (int ni = 0; ni < 2; ni++)
#pragma unroll
      for (int r = 0; r < 4; r++){
        int row = c0 + wm*64 + mi*16 + g*4 + r;   // c
        int col = j0 + wn*32 + ni*16 + r16;       // j
        Tb[row*HH + col] = acc[mi][ni][r];
      }
}

// ---------------- K5: pooled[b][c*32+d] = (1/denom[b][c]) * sum_j T[b][c][j]*w_v[j][h*32+d] ----------------
__global__ __launch_bounds__(256) void k_pool(const float* __restrict__ T,
                                              const float* __restrict__ wv,
                                              const float* __restrict__ denom,
                                              float* __restrict__ pooled){
  __shared__ float Tsh[64][65];
  __shared__ float wvsh[64][HH];
  const int b = blockIdx.x >> 2;
  const int c0 = (blockIdx.x & 3) * 64;
  const int t = threadIdx.x;
  const int cl = t >> 2, d0 = (t & 3) * 8;
  float acc[8];
#pragma unroll
  for (int i = 0; i < 8; i++) acc[i] = 0.f;

  for (int jc = 0; jc < HH; jc += 64){
    for (int idx = t; idx < 64*64; idx += 256){
      int rr = idx >> 6, cc = idx & 63;
      Tsh[rr][cc] = T[((size_t)b*NCC + c0 + rr)*HH + jc + cc];
    }
    for (int idx = t; idx < 64*HH; idx += 256){
      int rr = idx >> 8, cc = idx & 255;
      wvsh[rr][cc] = wv[(size_t)(jc + rr)*HH + cc];
    }
    __syncthreads();
    const int h = (c0 + cl) & 7;
    for (int j = 0; j < 64; j++){
      float tv = Tsh[cl][j];
      const float* wr = &wvsh[j][h*HDD + d0];
#pragma unroll
      for (int i = 0; i < 8; i++) acc[i] += tv * wr[i];
    }
    __syncthreads();
  }
  const int c = c0 + cl;
  float sc = 1.0f / denom[b*NCC + c];
#pragma unroll
  for (int i = 0; i < 8; i++)
    pooled[(size_t)b*8192 + c*HDD + d0 + i] = acc[i] * sc;
}

// ---------------- K6: h1pre[b][o] += sum over j-chunk of pooled[b][j]*w1[j][o] ----------------
__global__ __launch_bounds__(256) void k_mlp1(const float* __restrict__ pooled,
                                              const float* __restrict__ w1,
                                              float* __restrict__ h1pre){
  __shared__ float psh[8][256];
  const int b0 = (blockIdx.x >> 5) * 8;
  const int j0 = (blockIdx.x & 31) * 256;
  const int t = threadIdx.x;
  for (int idx = t; idx < 8*256; idx += 256){
    int bb = idx >> 8, jj = idx & 255;
    psh[bb][jj] = pooled[(size_t)(b0 + bb)*8192 + j0 + jj];
  }
  __syncthreads();
  float acc[8];
#pragma unroll
  for (int i = 0; i < 8; i++) acc[i] = 0.f;
  for (int jj = 0; jj < 256; jj++){
    float w = w1[(size_t)(j0 + jj)*HH + t];
#pragma unroll
    for (int bb = 0; bb < 8; bb++) acc[bb] += psh[bb][jj] * w;
  }
#pragma unroll
  for (int bb = 0; bb < 8; bb++) atomicAdd(&h1pre[(b0 + bb)*HH + t], acc[bb]);
}

// ---------------- K7: out = silu(h1pre + b1) @ w2 + b2 ----------------
__global__ __launch_bounds__(256) void k_mlp2(const float* __restrict__ h1pre,
                                              const float* __restrict__ b1,
                                              const float* __restrict__ w2,
                                              const float* __restrict__ b2,
                                              float* __restrict__ out){
  __shared__ float hsh[HH];
  const int b = blockIdx.x, t = threadIdx.x;
  float x = h1pre[b*HH + t] + b1[t];
  hsh[t] = x / (1.0f + __expf(-x));
  __syncthreads();
  float acc = b2[t];
  for (int j = 0; j < HH; j++) acc += hsh[j] * w2[j*HH + t];
  out[b*HH + t] = acc;
}

extern "C" void kernel_launch(void* const* d_in, const int* in_sizes, int n_in,
                              void* d_out, int out_size, void* d_ws, size_t ws_size,
                              hipStream_t stream) {
  const float* X     = (const float*)d_in[0];
  // d_in[1] edge_coords: provably unused (projection annihilates the coord-norm column)
  const int*   batch = (const int*)d_in[2];
  const float* seeds = (const float*)d_in[3];
  const float* wq    = (const float*)d_in[4];
  const float* wk    = (const float*)d_in[5];
  const float* wv    = (const float*)d_in[6];
  const float* w1    = (const float*)d_in[7];
  const float* b1    = (const float*)d_in[8];
  const float* w2    = (const float*)d_in[9];
  const float* b2    = (const float*)d_in[10];
  float* out = (float*)d_out;

  char* ws = (char*)d_ws;
  size_t off = 0;
  auto alloc = [&](size_t bytes) -> void* {
    void* p = ws + off;
    off = (off + bytes + 255) & ~(size_t)255;
    return p;
  };
  f16*   Xt     = (f16*)  alloc((size_t)NCC * EE * 2);   // 64 MiB
  f16*   Pt     = (f16*)  alloc((size_t)NCC * EE * 2);   // 64 MiB
  float* T      = (float*)alloc((size_t)BB * NCC * HH * 4); // 16 MiB
  float* qf     = (float*)alloc((size_t)SS * HH * 4);
  f16*   wsc    = (f16*)  alloc((size_t)NCC * HH * 2);
  int*   seg    = (int*)  alloc((size_t)(BB + 1) * 4);
  float* denom  = (float*)alloc((size_t)BB * NCC * 4);
  float* pooled = (float*)alloc((size_t)BB * 8192 * 4);
  float* h1pre  = (float*)alloc((size_t)BB * HH * 4);

  hipMemsetAsync(denom, 0, (size_t)BB * NCC * 4, stream);
  hipMemsetAsync(h1pre, 0, (size_t)BB * HH * 4, stream);

  k_seg  <<<EE/256, 256, 0, stream>>>(batch, seg);
  k_qproj<<<SS,     256, 0, stream>>>(seeds, wq, qf);
  k_wsc  <<<NCC,    256, 0, stream>>>(qf, wk, wsc);
  k_xt   <<<EE/64,  256, 0, stream>>>(X, Xt);
  k_gemm1<<<EE/128, 512, 0, stream>>>(wsc, X, batch, Pt, denom);
  k_gemm2<<<BB*4,   512, 0, stream>>>(Pt, Xt, seg, T);
  k_pool <<<BB*4,   256, 0, stream>>>(T, wv, denom, pooled);
  k_mlp1 <<<256,    256, 0, stream>>>(pooled, w1, h1pre);
  k_mlp2 <<<BB,     256, 0, stream>>>(h1pre, b1, w2, b2, out);
}

// Round 2
// 486.313 us; speedup vs baseline: 1.5788x; 1.5788x over previous
//
#include <hip/hip_runtime.h>
#include <hip/hip_bf16.h>

// Sizes (fixed by problem)
#define EE  131072   // edges
#define BB  64       // graphs
#define HH  256      // hidden
#define SS  32       // seeds
#define NHD 8        // heads
#define HDD 32       // head dim
#define NCC 256      // S*NH seed-head columns

typedef _Float16 f16;
typedef _Float16 f16x4 __attribute__((ext_vector_type(4)));
typedef float    f32x4 __attribute__((ext_vector_type(4)));
typedef unsigned short u16x8 __attribute__((ext_vector_type(8)));

static __device__ __forceinline__ unsigned short f2h(float x){
  f16 h = (f16)x; unsigned short u; __builtin_memcpy(&u, &h, 2); return u;
}
static __device__ __forceinline__ float h2f(unsigned short u){
  f16 h; __builtin_memcpy(&h, &u, 2); return (float)h;
}
static __device__ __forceinline__ unsigned int pk2(float a, float b){
  return (unsigned int)f2h(a) | ((unsigned int)f2h(b) << 16);
}

// ---------------- K0: segment offsets from sorted batch ----------------
__global__ __launch_bounds__(256) void k_seg(const int* __restrict__ batch, int* __restrict__ seg){
  int e = blockIdx.x * 256 + threadIdx.x;
  if (e == 0){ seg[0] = 0; seg[BB] = EE; }
  if (e > 0 && e < EE){
    int b = batch[e];
    if (batch[e-1] != b) seg[b] = e;
  }
}

// ---------------- K1a: q = seeds @ w_q ----------------
__global__ __launch_bounds__(256) void k_qproj(const float* __restrict__ seeds,
                                               const float* __restrict__ wq,
                                               float* __restrict__ qf){
  __shared__ float ssh[HH];
  int s = blockIdx.x, t = threadIdx.x;
  ssh[t] = seeds[s*HH + t];
  __syncthreads();
  float acc = 0.f;
  for (int j = 0; j < HH; j++) acc += ssh[j] * wq[j*HH + t];
  qf[s*HH + t] = acc;
}

// ---------------- K1b: WsC[c][j] = (1/sqrt(32)) * sum_d w_k[j][h*32+d]*q[s][h*32+d] ----------------
__global__ __launch_bounds__(256) void k_wsc(const float* __restrict__ qf,
                                             const float* __restrict__ wk,
                                             f16* __restrict__ wsc){
  int c = blockIdx.x, t = threadIdx.x;
  int s = c >> 3, h = c & 7;
  __shared__ float qsh[HDD];
  if (t < HDD) qsh[t] = qf[s*HH + h*HDD + t];
  __syncthreads();
  const float* wrow = wk + (size_t)t*HH + h*HDD;
  float acc = 0.f;
#pragma unroll
  for (int d = 0; d < HDD; d++) acc += qsh[d] * wrow[d];
  wsc[c*HH + t] = (f16)(acc * 0.17677669529663687f);  // 1/sqrt(32)
}

// ---------------- K2: Xt[j][e] = f16(X[e][j])  (256 x E, edge-contiguous) ----------------
__global__ __launch_bounds__(256) void k_xt(const float* __restrict__ X, f16* __restrict__ Xt){
  int e0 = blockIdx.x * 64;
  int t = threadIdx.x;
  f16* dst = Xt + (size_t)t*EE + e0;
#pragma unroll
  for (int w = 0; w < 8; w++){
    unsigned int u0 = pk2(X[(size_t)(e0 + w*8 + 0)*HH + t], X[(size_t)(e0 + w*8 + 1)*HH + t]);
    unsigned int u1 = pk2(X[(size_t)(e0 + w*8 + 2)*HH + t], X[(size_t)(e0 + w*8 + 3)*HH + t]);
    unsigned int u2 = pk2(X[(size_t)(e0 + w*8 + 4)*HH + t], X[(size_t)(e0 + w*8 + 5)*HH + t]);
    unsigned int u3 = pk2(X[(size_t)(e0 + w*8 + 6)*HH + t], X[(size_t)(e0 + w*8 + 7)*HH + t]);
    *(uint4*)(dst + w*8) = make_uint4(u0, u1, u2, u3);
  }
}

// ---------------- K3: GEMM1  St = WsC (256x256) x X^T (256xE), fused exp + Pt write + denom ----------------
// Block: 512 thr (8 waves, 4m x 2n), tile M=256(c) x N=128(e), BK=64, mfma 16x16x16_f16
__global__ __launch_bounds__(512) void k_gemm1(const f16* __restrict__ wsc,
                                               const float* __restrict__ X,
                                               const int* __restrict__ batch,
                                               f16* __restrict__ Pt,
                                               float* __restrict__ denom){
  __shared__ __align__(16) unsigned char smem[66048];
  int* bsh = (int*)(smem + 65536);
  const int tid = threadIdx.x;
  const int e0 = blockIdx.x * 128;
  if (tid < 128) bsh[tid] = batch[e0 + tid];

  const int lane = tid & 63, wid = tid >> 6;
  const int wm = wid >> 1, wn = wid & 1;   // 4 x 2 wave grid, wave tile 64x64
  const int r16 = lane & 15, g = lane >> 4;

  f32x4 acc[4][4];
#pragma unroll
  for (int i = 0; i < 4; i++)
#pragma unroll
    for (int j = 0; j < 4; j++) acc[i][j] = (f32x4){0.f, 0.f, 0.f, 0.f};

  for (int j0 = 0; j0 < HH; j0 += 64){
    // stage A: WsC[0..256)[j0..j0+64) -> smem[0..32768), swizzled
#pragma unroll
    for (int it = 0; it < 4; it++){
      int idx = tid + it*512;
      int row = idx >> 3, ch = idx & 7;
      uint4 v = *(const uint4*)(wsc + row*HH + j0 + ch*8);
      *(uint4*)(smem + row*128 + ((ch*16) ^ ((row & 7) << 4))) = v;
    }
    // stage B: X[e0..e0+128)[j0..j0+64) f32 -> f16, smem[32768..49152), swizzled
#pragma unroll
    for (int it = 0; it < 2; it++){
      int idx = tid + it*512;
      int er = idx >> 3, ch = idx & 7;
      const float* src = X + (size_t)(e0 + er)*HH + j0 + ch*8;
      float4 f0 = *(const float4*)src;
      float4 f1 = *(const float4*)(src + 4);
      uint4 hv = make_uint4(pk2(f0.x, f0.y), pk2(f0.z, f0.w), pk2(f1.x, f1.y), pk2(f1.z, f1.w));
      *(uint4*)(smem + 32768 + er*128 + ((ch*16) ^ ((er & 7) << 4))) = hv;
    }
    __syncthreads();
#pragma unroll
    for (int ks = 0; ks < 4; ks++){
      const int kb2 = (ks*16 + g*4) * 2;   // byte offset within 128B row
      f16x4 af[4], bf[4];
#pragma unroll
      for (int mi = 0; mi < 4; mi++){
        int row = wm*64 + mi*16 + r16;
        af[mi] = *(const f16x4*)(smem + row*128 + (kb2 ^ ((row & 7) << 4)));
      }
#pragma unroll
      for (int ni = 0; ni < 4; ni++){
        int row = wn*64 + ni*16 + r16;
        bf[ni] = *(const f16x4*)(smem + 32768 + row*128 + (kb2 ^ ((row & 7) << 4)));
      }
#pragma unroll
      for (int mi = 0; mi < 4; mi++)
#pragma unroll
        for (int ni = 0; ni < 4; ni++)
          acc[mi][ni] = __builtin_amdgcn_mfma_f32_16x16x16f16(af[mi], bf[ni], acc[mi][ni], 0, 0, 0);
    }
    __syncthreads();
  }

  // epilogue: scores -> smem (f16, 16B-granule swizzle), then exp + Pt + denom
#pragma unroll
  for (int mi = 0; mi < 4; mi++)
#pragma unroll
    for (int ni = 0; ni < 4; ni++)
#pragma unroll
      for (int r = 0; r < 4; r++){
        int row = wm*64 + mi*16 + g*4 + r;   // c
        int col = wn*64 + ni*16 + r16;       // e-local
        *(unsigned short*)(smem + row*256 + ((col*2) ^ ((row & 7) << 4))) = f2h(acc[mi][ni][r]);
      }
  __syncthreads();

  const int rowc = tid >> 1, half = tid & 1;
  float dsum = 0.f;
  int curb = bsh[half*64];
#pragma unroll
  for (int ch = 0; ch < 8; ch++){
    int ebase = half*64 + ch*8;
    uint4 v = *(const uint4*)(smem + rowc*256 + ((half*128 + ch*16) ^ ((rowc & 7) << 4)));
    u16x8 hv; __builtin_memcpy(&hv, &v, 16);
    float p[8];
#pragma unroll
    for (int i = 0; i < 8; i++){
      p[i] = __expf(h2f(hv[i]) - 4.0f);   // constant shift; cancels in normalization
      int b = bsh[ebase + i];
      if (b != curb){ atomicAdd(&denom[curb*NCC + rowc], dsum); dsum = 0.f; curb = b; }
      dsum += p[i];
    }
    uint4 o = make_uint4(pk2(p[0], p[1]), pk2(p[2], p[3]), pk2(p[4], p[5]), pk2(p[6], p[7]));
    *(uint4*)(Pt + (size_t)rowc*EE + e0 + ebase) = o;
  }
  atomicAdd(&denom[curb*NCC + rowc], dsum);
}

// ---------------- K4: GEMM2  T[b] = P_b^T (256 x E_b) x X_b (E_b x 256) ----------------
// Block: 512 thr (8 waves, 2m x 4n), tile 128(c) x 128(j), K over segment edges
__global__ __launch_bounds__(512) void k_gemm2(const f16* __restrict__ Pt,
                                               const f16* __restrict__ Xt,
                                               const int* __restrict__ seg,
                                               float* __restrict__ T){
  __shared__ __align__(16) unsigned char smem[32768];
  const int b  = blockIdx.x >> 2;
  const int c0 = ((blockIdx.x >> 1) & 1) * 128;
  const int j0 = (blockIdx.x & 1) * 128;
  const int beg = seg[b], end = seg[b + 1];
  const int kbeg = beg & ~63;
  const int nsteps = (end - kbeg + 63) >> 6;

  const int tid = threadIdx.x;
  const int lane = tid & 63, wid = tid >> 6;
  const int wm = wid >> 2, wn = wid & 3;   // wave tile 64(c) x 32(j)
  const int r16 = lane & 15, g = lane >> 4;

  f32x4 acc[4][2];
#pragma unroll
  for (int i = 0; i < 4; i++)
#pragma unroll
    for (int j = 0; j < 2; j++) acc[i][j] = (f32x4){0.f, 0.f, 0.f, 0.f};

  for (int st = 0; st < nsteps; st++){
    int kk = kbeg + st*64;
    // stage A: Pt rows c0..c0+128, edges kk..kk+64, mask outside [beg,end)
#pragma unroll
    for (int it = 0; it < 2; it++){
      int idx = tid + it*512;
      int cr = idx >> 3, ch = idx & 7;
      int eb = kk + ch*8;
      uint4 v = *(const uint4*)(Pt + (size_t)(c0 + cr)*EE + eb);
      if (eb < beg || eb + 8 > end){
        u16x8 hv; __builtin_memcpy(&hv, &v, 16);
#pragma unroll
        for (int i = 0; i < 8; i++) if (eb + i < beg || eb + i >= end) hv[i] = (unsigned short)0;
        __builtin_memcpy(&v, &hv, 16);
      }
      *(uint4*)(smem + cr*128 + ((ch*16) ^ ((cr & 7) << 4))) = v;
    }
    // stage B: Xt rows j0..j0+128 (no mask needed; A is zeroed outside segment)
#pragma unroll
    for (int it = 0; it < 2; it++){
      int idx = tid + it*512;
      int jr = idx >> 3, ch = idx & 7;
      uint4 v = *(const uint4*)(Xt + (size_t)(j0 + jr)*EE + kk + ch*8);
      *(uint4*)(smem + 16384 + jr*128 + ((ch*16) ^ ((jr & 7) << 4))) = v;
    }
    __syncthreads();
#pragma unroll
    for (int ks = 0; ks < 4; ks++){
      const int kb2 = (ks*16 + g*4) * 2;
      f16x4 af[4], bf[2];
#pragma unroll
      for (int mi = 0; mi < 4; mi++){
        int row = wm*64 + mi*16 + r16;
        af[mi] = *(const f16x4*)(smem + row*128 + (kb2 ^ ((row & 7) << 4)));
      }
#pragma unroll
      for (int ni = 0; ni < 2; ni++){
        int row = wn*32 + ni*16 + r16;
        bf[ni] = *(const f16x4*)(smem + 16384 + row*128 + (kb2 ^ ((row & 7) << 4)));
      }
#pragma unroll
      for (int mi = 0; mi < 4; mi++)
#pragma unroll
        for (int ni = 0; ni < 2; ni++)
          acc[mi][ni] = __builtin_amdgcn_mfma_f32_16x16x16f16(af[mi], bf[ni], acc[mi][ni], 0, 0, 0);
    }
    __syncthreads();
  }

  float* Tb = T + (size_t)b*NCC*HH;
#pragma unroll
  for (int mi = 0; mi < 4; mi++)
#pragma unroll
    for (int ni = 0; ni < 2; ni++)
#pragma unroll
      for (int r = 0; r < 4; r++){
        int row = c0 + wm*64 + mi*16 + g*4 + r;   // c
        int col = j0 + wn*32 + ni*16 + r16;       // j
        Tb[row*HH + col] = acc[mi][ni][r];
      }
}

// ---------------- K5: per-head GEMM  pooled[b,(s,h),d] = (1/denom) * sum_j T[b,(s,h),j]*wv[j,h*32+d]
// grid: (b,h) = 512 blocks, 256 threads. LDS: wv_h [256][36] (16B-aligned rows), T rows [32][257].
__global__ __launch_bounds__(256) void k_pool(const float* __restrict__ T,
                                              const float* __restrict__ wv,
                                              const float* __restrict__ denom,
                                              float* __restrict__ pooled){
  __shared__ float wvsh[256][36];   // 36 pad: rows stay 16B-aligned, banks rotate by 4/row
  __shared__ float Tsh[32][257];    // +1 pad
  const int b = blockIdx.x >> 3;
  const int h = blockIdx.x & 7;
  const int t = threadIdx.x;
  const int tr = t >> 3;          // 0..31
  const int tc = (t & 7) * 4;     // 0,4,...,28

#pragma unroll
  for (int p = 0; p < 8; p++){
    int j = tr + p*32;
    float4 wvv = *(const float4*)&wv[(size_t)j*HH + h*HDD + tc];
    *(float4*)&wvsh[j][tc] = wvv;
    float4 tv = *(const float4*)&T[((size_t)b*NCC + tr*NHD + h)*HH + tc + p*32];
    Tsh[tr][tc + p*32 + 0] = tv.x;
    Tsh[tr][tc + p*32 + 1] = tv.y;
    Tsh[tr][tc + p*32 + 2] = tv.z;
    Tsh[tr][tc + p*32 + 3] = tv.w;
  }
  __syncthreads();

  const int s = tr, d0 = tc;
  float ax = 0.f, ay = 0.f, az = 0.f, aw = 0.f;
#pragma unroll 4
  for (int j = 0; j < HH; j++){
    float tv = Tsh[s][j];
    float4 w4 = *(const float4*)&wvsh[j][d0];
    ax += tv * w4.x; ay += tv * w4.y; az += tv * w4.z; aw += tv * w4.w;
  }
  float sc = 1.0f / denom[b*NCC + s*NHD + h];
  float4 o = make_float4(ax*sc, ay*sc, az*sc, aw*sc);
  *(float4*)&pooled[(size_t)b*8192 + (size_t)(s*NHD + h)*HDD + d0] = o;
}

// ---------------- K6: h1pre[b][o] += sum over j-chunk of pooled[b][j]*w1[j][o] ----------------
__global__ __launch_bounds__(256) void k_mlp1(const float* __restrict__ pooled,
                                              const float* __restrict__ w1,
                                              float* __restrict__ h1pre){
  __shared__ float psh[8][256];
  const int b0 = (blockIdx.x >> 5) * 8;
  const int j0 = (blockIdx.x & 31) * 256;
  const int t = threadIdx.x;
  for (int idx = t; idx < 8*256; idx += 256){
    int bb = idx >> 8, jj = idx & 255;
    psh[bb][jj] = pooled[(size_t)(b0 + bb)*8192 + j0 + jj];
  }
  __syncthreads();
  float acc[8];
#pragma unroll
  for (int i = 0; i < 8; i++) acc[i] = 0.f;
  for (int jj = 0; jj < 256; jj++){
    float w = w1[(size_t)(j0 + jj)*HH + t];
#pragma unroll
    for (int bb = 0; bb < 8; bb++) acc[bb] += psh[bb][jj] * w;
  }
#pragma unroll
  for (int bb = 0; bb < 8; bb++) atomicAdd(&h1pre[(b0 + bb)*HH + t], acc[bb]);
}

// ---------------- K7: out = silu(h1pre + b1) @ w2 + b2 ----------------
__global__ __launch_bounds__(256) void k_mlp2(const float* __restrict__ h1pre,
                                              const float* __restrict__ b1,
                                              const float* __restrict__ w2,
                                              const float* __restrict__ b2,
                                              float* __restrict__ out){
  __shared__ float hsh[HH];
  const int b = blockIdx.x, t = threadIdx.x;
  float x = h1pre[b*HH + t] + b1[t];
  hsh[t] = x / (1.0f + __expf(-x));
  __syncthreads();
  float acc = b2[t];
  for (int j = 0; j < HH; j++) acc += hsh[j] * w2[j*HH + t];
  out[b*HH + t] = acc;
}

extern "C" void kernel_launch(void* const* d_in, const int* in_sizes, int n_in,
                              void* d_out, int out_size, void* d_ws, size_t ws_size,
                              hipStream_t stream) {
  const float* X     = (const float*)d_in[0];
  // d_in[1] edge_coords: provably unused (projection annihilates the coord-norm column)
  const int*   batch = (const int*)d_in[2];
  const float* seeds = (const float*)d_in[3];
  const float* wq    = (const float*)d_in[4];
  const float* wk    = (const float*)d_in[5];
  const float* wv    = (const float*)d_in[6];
  const float* w1    = (const float*)d_in[7];
  const float* b1    = (const float*)d_in[8];
  const float* w2    = (const float*)d_in[9];
  const float* b2    = (const float*)d_in[10];
  float* out = (float*)d_out;

  char* ws = (char*)d_ws;
  size_t off = 0;
  auto alloc = [&](size_t bytes) -> void* {
    void* p = ws + off;
    off = (off + bytes + 255) & ~(size_t)255;
    return p;
  };
  f16*   Xt     = (f16*)  alloc((size_t)NCC * EE * 2);   // 64 MiB
  f16*   Pt     = (f16*)  alloc((size_t)NCC * EE * 2);   // 64 MiB
  float* T      = (float*)alloc((size_t)BB * NCC * HH * 4); // 16 MiB
  float* qf     = (float*)alloc((size_t)SS * HH * 4);
  f16*   wsc    = (f16*)  alloc((size_t)NCC * HH * 2);
  int*   seg    = (int*)  alloc((size_t)(BB + 1) * 4);
  float* denom  = (float*)alloc((size_t)BB * NCC * 4);
  float* pooled = (float*)alloc((size_t)BB * 8192 * 4);
  float* h1pre  = (float*)alloc((size_t)BB * HH * 4);

  hipMemsetAsync(denom, 0, (size_t)BB * NCC * 4, stream);
  hipMemsetAsync(h1pre, 0, (size_t)BB * HH * 4, stream);

  k_seg  <<<EE/256, 256, 0, stream>>>(batch, seg);
  k_qproj<<<SS,     256, 0, stream>>>(seeds, wq, qf);
  k_wsc  <<<NCC,    256, 0, stream>>>(qf, wk, wsc);
  k_xt   <<<EE/64,  256, 0, stream>>>(X, Xt);
  k_gemm1<<<EE/128, 512, 0, stream>>>(wsc, X, batch, Pt, denom);
  k_gemm2<<<BB*4,   512, 0, stream>>>(Pt, Xt, seg, T);
  k_pool <<<BB*NHD, 256, 0, stream>>>(T, wv, denom, pooled);
  k_mlp1 <<<256,    256, 0, stream>>>(pooled, w1, h1pre);
  k_mlp2 <<<BB,     256, 0, stream>>>(h1pre, b1, w2, b2, out);
}

// Round 3
// 450.412 us; speedup vs baseline: 1.7047x; 1.0797x over previous
//
#include <hip/hip_runtime.h>
#include <hip/hip_bf16.h>

// Sizes (fixed by problem)
#define EE  131072   // edges
#define BB  64       // graphs
#define HH  256      // hidden
#define SS  32       // seeds
#define NHD 8        // heads
#define HDD 32       // head dim
#define NCC 256      // S*NH seed-head columns

typedef _Float16 f16;
typedef _Float16 f16x4 __attribute__((ext_vector_type(4)));
typedef float    f32x4 __attribute__((ext_vector_type(4)));
typedef unsigned short u16x8 __attribute__((ext_vector_type(8)));

static __device__ __forceinline__ unsigned short f2h(float x){
  f16 h = (f16)x; unsigned short u; __builtin_memcpy(&u, &h, 2); return u;
}
static __device__ __forceinline__ float h2f(unsigned short u){
  f16 h; __builtin_memcpy(&h, &u, 2); return (float)h;
}
static __device__ __forceinline__ unsigned int pk2(float a, float b){
  return (unsigned int)f2h(a) | ((unsigned int)f2h(b) << 16);
}

// ---------------- K0: segment offsets from sorted batch ----------------
__global__ __launch_bounds__(256) void k_seg(const int* __restrict__ batch, int* __restrict__ seg){
  int e = blockIdx.x * 256 + threadIdx.x;
  if (e == 0){ seg[0] = 0; seg[BB] = EE; }
  if (e > 0 && e < EE){
    int b = batch[e];
    if (batch[e-1] != b) seg[b] = e;
  }
}

// ---------------- K1a: q = seeds @ w_q ----------------
__global__ __launch_bounds__(256) void k_qproj(const float* __restrict__ seeds,
                                               const float* __restrict__ wq,
                                               float* __restrict__ qf){
  __shared__ float ssh[HH];
  int s = blockIdx.x, t = threadIdx.x;
  ssh[t] = seeds[s*HH + t];
  __syncthreads();
  float acc = 0.f;
  for (int j = 0; j < HH; j++) acc += ssh[j] * wq[j*HH + t];
  qf[s*HH + t] = acc;
}

// ---------------- K1b: WsC[c][j] = (1/sqrt(32)) * sum_d w_k[j][h*32+d]*q[s][h*32+d] ----------------
__global__ __launch_bounds__(256) void k_wsc(const float* __restrict__ qf,
                                             const float* __restrict__ wk,
                                             f16* __restrict__ wsc){
  int c = blockIdx.x, t = threadIdx.x;
  int s = c >> 3, h = c & 7;
  __shared__ float qsh[HDD];
  if (t < HDD) qsh[t] = qf[s*HH + h*HDD + t];
  __syncthreads();
  const float* wrow = wk + (size_t)t*HH + h*HDD;
  float acc = 0.f;
#pragma unroll
  for (int d = 0; d < HDD; d++) acc += qsh[d] * wrow[d];
  wsc[c*HH + t] = (f16)(acc * 0.17677669529663687f);  // 1/sqrt(32)
}

// ---------------- K2: Xt[j][e] = f16(X[e][j])  (256 x E, edge-contiguous) ----------------
// LDS-tiled transpose: 256e x 256j per block, 4 looped 64j sub-tiles.
// Phase 1: coalesced float4 reads, conflict-free b32 LDS writes (e-pairs packed).
// Phase 2: 4x b32 LDS gather -> fully coalesced uint4 global writes (wave = 2 rows).
__global__ __launch_bounds__(256) void k_xt(const float* __restrict__ X, f16* __restrict__ Xt){
  __shared__ __align__(16) unsigned char lds[64 * 516 + 16];  // 64 j-rows, 516B stride
  const int e0 = blockIdx.x * 256;
  const int t  = threadIdx.x;
  const int f4 = t & 15, t4 = t >> 4;
  const int jr2 = t >> 5;        // 0..7  (phase 2)
  const int c16 = t & 31;        // 16B chunk (phase 2)

  for (int jt = 0; jt < 4; jt++){
    const int j0 = jt * 64;
    if (jt) __syncthreads();
    // phase 1: element (j, e) packed with (j, e+1) into one u32 at word j*129 + e/2
    unsigned* wbase = (unsigned*)lds;
#pragma unroll
    for (int p = 0; p < 8; p++){
      int e = p*32 + 2*t4;
      const float* s0 = X + (size_t)(e0 + e)*HH + j0 + f4*4;
      float4 a = *(const float4*)s0;
      float4 b = *(const float4*)(s0 + HH);
      int wb = e >> 1;
      wbase[(f4*4+0)*129 + wb] = pk2(a.x, b.x);
      wbase[(f4*4+1)*129 + wb] = pk2(a.y, b.y);
      wbase[(f4*4+2)*129 + wb] = pk2(a.z, b.z);
      wbase[(f4*4+3)*129 + wb] = pk2(a.w, b.w);
    }
    __syncthreads();
    // phase 2: wave covers 2 full 512B Xt rows -> coalesced
    const unsigned* rbase = (const unsigned*)lds;
#pragma unroll
    for (int ji = 0; ji < 8; ji++){
      int j = ji*8 + jr2;
      int w = j*129 + c16*4;
      uint4 v = make_uint4(rbase[w], rbase[w+1], rbase[w+2], rbase[w+3]);
      *(uint4*)(Xt + (size_t)(j0 + j)*EE + e0 + c16*8) = v;
    }
  }
}

// ---------------- K3: GEMM1  St = WsC (256x256) x X^T (256xE), fused exp + Pt write + denom ----------------
// Block: 512 thr (8 waves, 4m x 2n), tile M=256(c) x N=128(e), BK=64, mfma 16x16x16_f16
__global__ __launch_bounds__(512) void k_gemm1(const f16* __restrict__ wsc,
                                               const float* __restrict__ X,
                                               const int* __restrict__ batch,
                                               f16* __restrict__ Pt,
                                               float* __restrict__ denom){
  __shared__ __align__(16) unsigned char smem[66048];
  int* bsh = (int*)(smem + 65536);
  const int tid = threadIdx.x;
  const int e0 = blockIdx.x * 128;
  if (tid < 128) bsh[tid] = batch[e0 + tid];

  const int lane = tid & 63, wid = tid >> 6;
  const int wm = wid >> 1, wn = wid & 1;   // 4 x 2 wave grid, wave tile 64x64
  const int r16 = lane & 15, g = lane >> 4;

  f32x4 acc[4][4];
#pragma unroll
  for (int i = 0; i < 4; i++)
#pragma unroll
    for (int j = 0; j < 4; j++) acc[i][j] = (f32x4){0.f, 0.f, 0.f, 0.f};

  for (int j0 = 0; j0 < HH; j0 += 64){
    // stage A: WsC[0..256)[j0..j0+64) -> smem[0..32768), swizzled
#pragma unroll
    for (int it = 0; it < 4; it++){
      int idx = tid + it*512;
      int row = idx >> 3, ch = idx & 7;
      uint4 v = *(const uint4*)(wsc + row*HH + j0 + ch*8);
      *(uint4*)(smem + row*128 + ((ch*16) ^ ((row & 7) << 4))) = v;
    }
    // stage B: X[e0..e0+128)[j0..j0+64) f32 -> f16, smem[32768..49152), swizzled
#pragma unroll
    for (int it = 0; it < 2; it++){
      int idx = tid + it*512;
      int er = idx >> 3, ch = idx & 7;
      const float* src = X + (size_t)(e0 + er)*HH + j0 + ch*8;
      float4 f0 = *(const float4*)src;
      float4 f1 = *(const float4*)(src + 4);
      uint4 hv = make_uint4(pk2(f0.x, f0.y), pk2(f0.z, f0.w), pk2(f1.x, f1.y), pk2(f1.z, f1.w));
      *(uint4*)(smem + 32768 + er*128 + ((ch*16) ^ ((er & 7) << 4))) = hv;
    }
    __syncthreads();
#pragma unroll
    for (int ks = 0; ks < 4; ks++){
      const int kb2 = (ks*16 + g*4) * 2;   // byte offset within 128B row
      f16x4 af[4], bf[4];
#pragma unroll
      for (int mi = 0; mi < 4; mi++){
        int row = wm*64 + mi*16 + r16;
        af[mi] = *(const f16x4*)(smem + row*128 + (kb2 ^ ((row & 7) << 4)));
      }
#pragma unroll
      for (int ni = 0; ni < 4; ni++){
        int row = wn*64 + ni*16 + r16;
        bf[ni] = *(const f16x4*)(smem + 32768 + row*128 + (kb2 ^ ((row & 7) << 4)));
      }
#pragma unroll
      for (int mi = 0; mi < 4; mi++)
#pragma unroll
        for (int ni = 0; ni < 4; ni++)
          acc[mi][ni] = __builtin_amdgcn_mfma_f32_16x16x16f16(af[mi], bf[ni], acc[mi][ni], 0, 0, 0);
    }
    __syncthreads();
  }

  // epilogue: scores -> smem (f16, 16B-granule swizzle), then exp + Pt + denom
#pragma unroll
  for (int mi = 0; mi < 4; mi++)
#pragma unroll
    for (int ni = 0; ni < 4; ni++)
#pragma unroll
      for (int r = 0; r < 4; r++){
        int row = wm*64 + mi*16 + g*4 + r;   // c
        int col = wn*64 + ni*16 + r16;       // e-local
        *(unsigned short*)(smem + row*256 + ((col*2) ^ ((row & 7) << 4))) = f2h(acc[mi][ni][r]);
      }
  __syncthreads();

  const int rowc = tid >> 1, half = tid & 1;
  float dsum = 0.f;
  int curb = bsh[half*64];
#pragma unroll
  for (int ch = 0; ch < 8; ch++){
    int ebase = half*64 + ch*8;
    uint4 v = *(const uint4*)(smem + rowc*256 + ((half*128 + ch*16) ^ ((rowc & 7) << 4)));
    u16x8 hv; __builtin_memcpy(&hv, &v, 16);
    float p[8];
#pragma unroll
    for (int i = 0; i < 8; i++){
      p[i] = __expf(h2f(hv[i]) - 4.0f);   // constant shift; cancels in normalization
      int b = bsh[ebase + i];
      if (b != curb){ atomicAdd(&denom[curb*NCC + rowc], dsum); dsum = 0.f; curb = b; }
      dsum += p[i];
    }
    uint4 o = make_uint4(pk2(p[0], p[1]), pk2(p[2], p[3]), pk2(p[4], p[5]), pk2(p[6], p[7]));
    *(uint4*)(Pt + (size_t)rowc*EE + e0 + ebase) = o;
  }
  atomicAdd(&denom[curb*NCC + rowc], dsum);
}

// ---------------- K4: GEMM2  T[b] = P_b^T (256 x E_b) x X_b (E_b x 256) ----------------
// Block: 512 thr (8 waves, 2m x 4n), tile 128(c) x 128(j), K over segment edges
__global__ __launch_bounds__(512) void k_gemm2(const f16* __restrict__ Pt,
                                               const f16* __restrict__ Xt,
                                               const int* __restrict__ seg,
                                               float* __restrict__ T){
  __shared__ __align__(16) unsigned char smem[32768];
  const int b  = blockIdx.x >> 2;
  const int c0 = ((blockIdx.x >> 1) & 1) * 128;
  const int j0 = (blockIdx.x & 1) * 128;
  const int beg = seg[b], end = seg[b + 1];
  const int kbeg = beg & ~63;
  const int nsteps = (end - kbeg + 63) >> 6;

  const int tid = threadIdx.x;
  const int lane = tid & 63, wid = tid >> 6;
  const int wm = wid >> 2, wn = wid & 3;   // wave tile 64(c) x 32(j)
  const int r16 = lane & 15, g = lane >> 4;

  f32x4 acc[4][2];
#pragma unroll
  for (int i = 0; i < 4; i++)
#pragma unroll
    for (int j = 0; j < 2; j++) acc[i][j] = (f32x4){0.f, 0.f, 0.f, 0.f};

  for (int st = 0; st < nsteps; st++){
    int kk = kbeg + st*64;
    // stage A: Pt rows c0..c0+128, edges kk..kk+64, mask outside [beg,end)
#pragma unroll
    for (int it = 0; it < 2; it++){
      int idx = tid + it*512;
      int cr = idx >> 3, ch = idx & 7;
      int eb = kk + ch*8;
      uint4 v = *(const uint4*)(Pt + (size_t)(c0 + cr)*EE + eb);
      if (eb < beg || eb + 8 > end){
        u16x8 hv; __builtin_memcpy(&hv, &v, 16);
#pragma unroll
        for (int i = 0; i < 8; i++) if (eb + i < beg || eb + i >= end) hv[i] = (unsigned short)0;
        __builtin_memcpy(&v, &hv, 16);
      }
      *(uint4*)(smem + cr*128 + ((ch*16) ^ ((cr & 7) << 4))) = v;
    }
    // stage B: Xt rows j0..j0+128 (no mask needed; A is zeroed outside segment)
#pragma unroll
    for (int it = 0; it < 2; it++){
      int idx = tid + it*512;
      int jr = idx >> 3, ch = idx & 7;
      uint4 v = *(const uint4*)(Xt + (size_t)(j0 + jr)*EE + kk + ch*8);
      *(uint4*)(smem + 16384 + jr*128 + ((ch*16) ^ ((jr & 7) << 4))) = v;
    }
    __syncthreads();
#pragma unroll
    for (int ks = 0; ks < 4; ks++){
      const int kb2 = (ks*16 + g*4) * 2;
      f16x4 af[4], bf[2];
#pragma unroll
      for (int mi = 0; mi < 4; mi++){
        int row = wm*64 + mi*16 + r16;
        af[mi] = *(const f16x4*)(smem + row*128 + (kb2 ^ ((row & 7) << 4)));
      }
#pragma unroll
      for (int ni = 0; ni < 2; ni++){
        int row = wn*32 + ni*16 + r16;
        bf[ni] = *(const f16x4*)(smem + 16384 + row*128 + (kb2 ^ ((row & 7) << 4)));
      }
#pragma unroll
      for (int mi = 0; mi < 4; mi++)
#pragma unroll
        for (int ni = 0; ni < 2; ni++)
          acc[mi][ni] = __builtin_amdgcn_mfma_f32_16x16x16f16(af[mi], bf[ni], acc[mi][ni], 0, 0, 0);
    }
    __syncthreads();
  }

  float* Tb = T + (size_t)b*NCC*HH;
#pragma unroll
  for (int mi = 0; mi < 4; mi++)
#pragma unroll
    for (int ni = 0; ni < 2; ni++)
#pragma unroll
      for (int r = 0; r < 4; r++){
        int row = c0 + wm*64 + mi*16 + g*4 + r;   // c
        int col = j0 + wn*32 + ni*16 + r16;       // j
        Tb[row*HH + col] = acc[mi][ni][r];
      }
}

// ---------------- K5: per-head GEMM  pooled[b,(s,h),d] = (1/denom) * sum_j T[b,(s,h),j]*wv[j,h*32+d]
// grid: (b,h) = 512 blocks, 256 threads. LDS: wv_h [256][36] (16B-aligned rows), T rows [32][257].
__global__ __launch_bounds__(256) void k_pool(const float* __restrict__ T,
                                              const float* __restrict__ wv,
                                              const float* __restrict__ denom,
                                              float* __restrict__ pooled){
  __shared__ float wvsh[256][36];   // 36 pad: rows stay 16B-aligned, banks rotate by 4/row
  __shared__ float Tsh[32][257];    // +1 pad
  const int b = blockIdx.x >> 3;
  const int h = blockIdx.x & 7;
  const int t = threadIdx.x;
  const int tr = t >> 3;          // 0..31
  const int tc = (t & 7) * 4;     // 0,4,...,28

#pragma unroll
  for (int p = 0; p < 8; p++){
    int j = tr + p*32;
    float4 wvv = *(const float4*)&wv[(size_t)j*HH + h*HDD + tc];
    *(float4*)&wvsh[j][tc] = wvv;
    float4 tv = *(const float4*)&T[((size_t)b*NCC + tr*NHD + h)*HH + tc + p*32];
    Tsh[tr][tc + p*32 + 0] = tv.x;
    Tsh[tr][tc + p*32 + 1] = tv.y;
    Tsh[tr][tc + p*32 + 2] = tv.z;
    Tsh[tr][tc + p*32 + 3] = tv.w;
  }
  __syncthreads();

  const int s = tr, d0 = tc;
  float ax = 0.f, ay = 0.f, az = 0.f, aw = 0.f;
#pragma unroll 4
  for (int j = 0; j < HH; j++){
    float tv = Tsh[s][j];
    float4 w4 = *(const float4*)&wvsh[j][d0];
    ax += tv * w4.x; ay += tv * w4.y; az += tv * w4.z; aw += tv * w4.w;
  }
  float sc = 1.0f / denom[b*NCC + s*NHD + h];
  float4 o = make_float4(ax*sc, ay*sc, az*sc, aw*sc);
  *(float4*)&pooled[(size_t)b*8192 + (size_t)(s*NHD + h)*HDD + d0] = o;
}

// ---------------- K6: h1pre[b][o] += sum over j-chunk of pooled[b][j]*w1[j][o] ----------------
__global__ __launch_bounds__(256) void k_mlp1(const float* __restrict__ pooled,
                                              const float* __restrict__ w1,
                                              float* __restrict__ h1pre){
  __shared__ float psh[8][256];
  const int b0 = (blockIdx.x >> 5) * 8;
  const int j0 = (blockIdx.x & 31) * 256;
  const int t = threadIdx.x;
  for (int idx = t; idx < 8*256; idx += 256){
    int bb = idx >> 8, jj = idx & 255;
    psh[bb][jj] = pooled[(size_t)(b0 + bb)*8192 + j0 + jj];
  }
  __syncthreads();
  float acc[8];
#pragma unroll
  for (int i = 0; i < 8; i++) acc[i] = 0.f;
  for (int jj = 0; jj < 256; jj++){
    float w = w1[(size_t)(j0 + jj)*HH + t];
#pragma unroll
    for (int bb = 0; bb < 8; bb++) acc[bb] += psh[bb][jj] * w;
  }
#pragma unroll
  for (int bb = 0; bb < 8; bb++) atomicAdd(&h1pre[(b0 + bb)*HH + t], acc[bb]);
}

// ---------------- K7: out = silu(h1pre + b1) @ w2 + b2 ----------------
__global__ __launch_bounds__(256) void k_mlp2(const float* __restrict__ h1pre,
                                              const float* __restrict__ b1,
                                              const float* __restrict__ w2,
                                              const float* __restrict__ b2,
                                              float* __restrict__ out){
  __shared__ float hsh[HH];
  const int b = blockIdx.x, t = threadIdx.x;
  float x = h1pre[b*HH + t] + b1[t];
  hsh[t] = x / (1.0f + __expf(-x));
  __syncthreads();
  float acc = b2[t];
  for (int j = 0; j < HH; j++) acc += hsh[j] * w2[j*HH + t];
  out[b*HH + t] = acc;
}

extern "C" void kernel_launch(void* const* d_in, const int* in_sizes, int n_in,
                              void* d_out, int out_size, void* d_ws, size_t ws_size,
                              hipStream_t stream) {
  const float* X     = (const float*)d_in[0];
  // d_in[1] edge_coords: provably unused (projection annihilates the coord-norm column)
  const int*   batch = (const int*)d_in[2];
  const float* seeds = (const float*)d_in[3];
  const float* wq    = (const float*)d_in[4];
  const float* wk    = (const float*)d_in[5];
  const float* wv    = (const float*)d_in[6];
  const float* w1    = (const float*)d_in[7];
  const float* b1    = (const float*)d_in[8];
  const float* w2    = (const float*)d_in[9];
  const float* b2    = (const float*)d_in[10];
  float* out = (float*)d_out;

  char* ws = (char*)d_ws;
  size_t off = 0;
  auto alloc = [&](size_t bytes) -> void* {
    void* p = ws + off;
    off = (off + bytes + 255) & ~(size_t)255;
    return p;
  };
  f16*   Xt     = (f16*)  alloc((size_t)NCC * EE * 2);   // 64 MiB
  f16*   Pt     = (f16*)  alloc((size_t)NCC * EE * 2);   // 64 MiB
  float* T      = (float*)alloc((size_t)BB * NCC * HH * 4); // 16 MiB
  float* qf     = (float*)alloc((size_t)SS * HH * 4);
  f16*   wsc    = (f16*)  alloc((size_t)NCC * HH * 2);
  int*   seg    = (int*)  alloc((size_t)(BB + 1) * 4);
  float* denom  = (float*)alloc((size_t)BB * NCC * 4);
  float* pooled = (float*)alloc((size_t)BB * 8192 * 4);
  float* h1pre  = (float*)alloc((size_t)BB * HH * 4);

  hipMemsetAsync(denom, 0, (size_t)BB * NCC * 4, stream);
  hipMemsetAsync(h1pre, 0, (size_t)BB * HH * 4, stream);

  k_seg  <<<EE/256, 256, 0, stream>>>(batch, seg);
  k_qproj<<<SS,     256, 0, stream>>>(seeds, wq, qf);
  k_wsc  <<<NCC,    256, 0, stream>>>(qf, wk, wsc);
  k_xt   <<<EE/256, 256, 0, stream>>>(X, Xt);
  k_gemm1<<<EE/128, 512, 0, stream>>>(wsc, X, batch, Pt, denom);
  k_gemm2<<<BB*4,   512, 0, stream>>>(Pt, Xt, seg, T);
  k_pool <<<BB*NHD, 256, 0, stream>>>(T, wv, denom, pooled);
  k_mlp1 <<<256,    256, 0, stream>>>(pooled, w1, h1pre);
  k_mlp2 <<<BB,     256, 0, stream>>>(h1pre, b1, w2, b2, out);
}

// Round 4
// 445.788 us; speedup vs baseline: 1.7223x; 1.0104x over previous
//
#include <hip/hip_runtime.h>
#include <hip/hip_bf16.h>

// Sizes (fixed by problem)
#define EE  131072   // edges
#define BB  64       // graphs
#define HH  256      // hidden
#define SS  32       // seeds
#define NHD 8        // heads
#define HDD 32       // head dim
#define NCC 256      // S*NH seed-head columns

typedef _Float16 f16;
typedef _Float16 f16x4 __attribute__((ext_vector_type(4)));
typedef _Float16 f16x8 __attribute__((ext_vector_type(8)));
typedef float    f32x4 __attribute__((ext_vector_type(4)));
typedef unsigned short u16x8 __attribute__((ext_vector_type(8)));

static __device__ __forceinline__ unsigned short f2h(float x){
  f16 h = (f16)x; unsigned short u; __builtin_memcpy(&u, &h, 2); return u;
}
static __device__ __forceinline__ float h2f(unsigned short u){
  f16 h; __builtin_memcpy(&h, &u, 2); return (float)h;
}
static __device__ __forceinline__ unsigned int pk2(float a, float b){
  return (unsigned int)f2h(a) | ((unsigned int)f2h(b) << 16);
}
static __device__ __forceinline__ uint4 maskseg(uint4 v, int eb, int beg, int end){
  u16x8 hv; __builtin_memcpy(&hv, &v, 16);
#pragma unroll
  for (int i = 0; i < 8; i++) if (eb + i < beg || eb + i >= end) hv[i] = (unsigned short)0;
  __builtin_memcpy(&v, &hv, 16);
  return v;
}

// ---------------- K0: segment offsets from sorted batch ----------------
__global__ __launch_bounds__(256) void k_seg(const int* __restrict__ batch, int* __restrict__ seg){
  int e = blockIdx.x * 256 + threadIdx.x;
  if (e == 0){ seg[0] = 0; seg[BB] = EE; }
  if (e > 0 && e < EE){
    int b = batch[e];
    if (batch[e-1] != b) seg[b] = e;
  }
}

// ---------------- K1a: q = seeds @ w_q ----------------
__global__ __launch_bounds__(256) void k_qproj(const float* __restrict__ seeds,
                                               const float* __restrict__ wq,
                                               float* __restrict__ qf){
  __shared__ float ssh[HH];
  int s = blockIdx.x, t = threadIdx.x;
  ssh[t] = seeds[s*HH + t];
  __syncthreads();
  float acc = 0.f;
  for (int j = 0; j < HH; j++) acc += ssh[j] * wq[j*HH + t];
  qf[s*HH + t] = acc;
}

// ---------------- K1b: WsC[c][j] = (1/sqrt(32)) * sum_d w_k[j][h*32+d]*q[s][h*32+d] ----------------
__global__ __launch_bounds__(256) void k_wsc(const float* __restrict__ qf,
                                             const float* __restrict__ wk,
                                             f16* __restrict__ wsc){
  int c = blockIdx.x, t = threadIdx.x;
  int s = c >> 3, h = c & 7;
  __shared__ float qsh[HDD];
  if (t < HDD) qsh[t] = qf[s*HH + h*HDD + t];
  __syncthreads();
  const float* wrow = wk + (size_t)t*HH + h*HDD;
  float acc = 0.f;
#pragma unroll
  for (int d = 0; d < HDD; d++) acc += qsh[d] * wrow[d];
  wsc[c*HH + t] = (f16)(acc * 0.17677669529663687f);  // 1/sqrt(32)
}

// ---------------- K2: Xt[j][e] = f16(X[e][j])  (256 x E, edge-contiguous) ----------------
__global__ __launch_bounds__(256) void k_xt(const float* __restrict__ X, f16* __restrict__ Xt){
  __shared__ __align__(16) unsigned char lds[64 * 516 + 16];  // 64 j-rows, 516B stride
  const int e0 = blockIdx.x * 256;
  const int t  = threadIdx.x;
  const int f4 = t & 15, t4 = t >> 4;
  const int jr2 = t >> 5;        // 0..7  (phase 2)
  const int c16 = t & 31;        // 16B chunk (phase 2)

  for (int jt = 0; jt < 4; jt++){
    const int j0 = jt * 64;
    if (jt) __syncthreads();
    unsigned* wbase = (unsigned*)lds;
#pragma unroll
    for (int p = 0; p < 8; p++){
      int e = p*32 + 2*t4;
      const float* s0 = X + (size_t)(e0 + e)*HH + j0 + f4*4;
      float4 a = *(const float4*)s0;
      float4 b = *(const float4*)(s0 + HH);
      int wb = e >> 1;
      wbase[(f4*4+0)*129 + wb] = pk2(a.x, b.x);
      wbase[(f4*4+1)*129 + wb] = pk2(a.y, b.y);
      wbase[(f4*4+2)*129 + wb] = pk2(a.z, b.z);
      wbase[(f4*4+3)*129 + wb] = pk2(a.w, b.w);
    }
    __syncthreads();
    const unsigned* rbase = (const unsigned*)lds;
#pragma unroll
    for (int ji = 0; ji < 8; ji++){
      int j = ji*8 + jr2;
      int w = j*129 + c16*4;
      uint4 v = make_uint4(rbase[w], rbase[w+1], rbase[w+2], rbase[w+3]);
      *(uint4*)(Xt + (size_t)(j0 + j)*EE + e0 + c16*8) = v;
    }
  }
}

// ---------------- K3: GEMM1  St = WsC (256x256) x X^T (256xE), fused exp + Pt write + denom ----------------
// 512 thr (8 waves, 4m x 2n), tile M=256(c) x N=128(e), BK=64, mfma 16x16x32_f16.
// T14 pipeline: prefetch next K-step's A/B into regs before compute of current step.
__global__ __launch_bounds__(512) void k_gemm1(const f16* __restrict__ wsc,
                                               const float* __restrict__ X,
                                               const int* __restrict__ batch,
                                               f16* __restrict__ Pt,
                                               float* __restrict__ denom){
  __shared__ __align__(16) unsigned char smem[66048];
  int* bsh = (int*)(smem + 65536);
  const int tid = threadIdx.x;
  const int e0 = blockIdx.x * 128;
  if (tid < 128) bsh[tid] = batch[e0 + tid];

  const int lane = tid & 63, wid = tid >> 6;
  const int wm = wid >> 1, wn = wid & 1;   // 4 x 2 wave grid, wave tile 64x64
  const int r16 = lane & 15, g = lane >> 4;
  const int cr = tid >> 3, ch = tid & 7;   // staging coords

  f32x4 acc[4][4];
#pragma unroll
  for (int i = 0; i < 4; i++)
#pragma unroll
    for (int j = 0; j < 4; j++) acc[i][j] = (f32x4){0.f, 0.f, 0.f, 0.f};

  uint4 qa[4];
  float4 qb[4];

  // prefetch j0 = 0
#pragma unroll
  for (int i = 0; i < 4; i++)
    qa[i] = *(const uint4*)(wsc + (size_t)(cr + i*64)*HH + 0 + ch*8);
  {
    const float* s0 = X + (size_t)(e0 + cr)*HH + 0 + ch*8;
    const float* s1 = X + (size_t)(e0 + cr + 64)*HH + 0 + ch*8;
    qb[0] = *(const float4*)s0; qb[1] = *(const float4*)(s0 + 4);
    qb[2] = *(const float4*)s1; qb[3] = *(const float4*)(s1 + 4);
  }

  for (int jt = 0; jt < 4; jt++){
    if (jt) __syncthreads();   // prior compute done reading smem
    // write staged regs -> LDS (swizzled)
#pragma unroll
    for (int i = 0; i < 4; i++)
      *(uint4*)(smem + (cr + i*64)*128 + ((ch*16) ^ ((cr & 7) << 4))) = qa[i];
    {
      uint4 h0 = make_uint4(pk2(qb[0].x,qb[0].y), pk2(qb[0].z,qb[0].w), pk2(qb[1].x,qb[1].y), pk2(qb[1].z,qb[1].w));
      uint4 h1 = make_uint4(pk2(qb[2].x,qb[2].y), pk2(qb[2].z,qb[2].w), pk2(qb[3].x,qb[3].y), pk2(qb[3].z,qb[3].w));
      *(uint4*)(smem + 32768 + cr*128        + ((ch*16) ^ ((cr & 7) << 4))) = h0;
      *(uint4*)(smem + 32768 + (cr+64)*128   + ((ch*16) ^ ((cr & 7) << 4))) = h1;
    }
    // prefetch next step
    if (jt < 3){
      int j0 = (jt + 1) * 64;
#pragma unroll
      for (int i = 0; i < 4; i++)
        qa[i] = *(const uint4*)(wsc + (size_t)(cr + i*64)*HH + j0 + ch*8);
      const float* s0 = X + (size_t)(e0 + cr)*HH + j0 + ch*8;
      const float* s1 = X + (size_t)(e0 + cr + 64)*HH + j0 + ch*8;
      qb[0] = *(const float4*)s0; qb[1] = *(const float4*)(s0 + 4);
      qb[2] = *(const float4*)s1; qb[3] = *(const float4*)(s1 + 4);
    }
    __syncthreads();
    // compute: 2 x K=32 sub-steps
#pragma unroll
    for (int ks = 0; ks < 2; ks++){
      f16x8 af[4], bf[4];
#pragma unroll
      for (int mi = 0; mi < 4; mi++){
        int row = wm*64 + mi*16 + r16;
        af[mi] = *(const f16x8*)(smem + row*128 + ((((ks*4 + g)*16)) ^ ((row & 7) << 4)));
      }
#pragma unroll
      for (int ni = 0; ni < 4; ni++){
        int row = wn*64 + ni*16 + r16;
        bf[ni] = *(const f16x8*)(smem + 32768 + row*128 + ((((ks*4 + g)*16)) ^ ((row & 7) << 4)));
      }
#pragma unroll
      for (int mi = 0; mi < 4; mi++)
#pragma unroll
        for (int ni = 0; ni < 4; ni++)
          acc[mi][ni] = __builtin_amdgcn_mfma_f32_16x16x32_f16(af[mi], bf[ni], acc[mi][ni], 0, 0, 0);
    }
  }
  __syncthreads();   // before epilogue reuses smem

  // epilogue: scores -> smem (f16, 16B-granule swizzle), then exp + Pt + denom
#pragma unroll
  for (int mi = 0; mi < 4; mi++)
#pragma unroll
    for (int ni = 0; ni < 4; ni++)
#pragma unroll
      for (int r = 0; r < 4; r++){
        int row = wm*64 + mi*16 + g*4 + r;   // c
        int col = wn*64 + ni*16 + r16;       // e-local
        *(unsigned short*)(smem + row*256 + ((col*2) ^ ((row & 7) << 4))) = f2h(acc[mi][ni][r]);
      }
  __syncthreads();

  const int rowc = tid >> 1, half = tid & 1;
  float dsum = 0.f;
  int curb = bsh[half*64];
#pragma unroll
  for (int cc = 0; cc < 8; cc++){
    int ebase = half*64 + cc*8;
    uint4 v = *(const uint4*)(smem + rowc*256 + ((half*128 + cc*16) ^ ((rowc & 7) << 4)));
    u16x8 hv; __builtin_memcpy(&hv, &v, 16);
    float p[8];
#pragma unroll
    for (int i = 0; i < 8; i++){
      p[i] = __expf(h2f(hv[i]) - 4.0f);   // constant shift; cancels in normalization
      int b = bsh[ebase + i];
      if (b != curb){ atomicAdd(&denom[curb*NCC + rowc], dsum); dsum = 0.f; curb = b; }
      dsum += p[i];
    }
    uint4 o = make_uint4(pk2(p[0], p[1]), pk2(p[2], p[3]), pk2(p[4], p[5]), pk2(p[6], p[7]));
    *(uint4*)(Pt + (size_t)rowc*EE + e0 + ebase) = o;
  }
  atomicAdd(&denom[curb*NCC + rowc], dsum);
}

// ---------------- K4: GEMM2  T[b] += P_b^T (256 x E_b) x X_b (E_b x 256) ----------------
// grid: b(64) x quadrant(4) x kc(2) = 512 blocks, 2/CU. Split-K accumulates into
// zeroed T via f32 atomics. T14 reg-prefetch pipeline; mfma 16x16x32_f16.
__global__ __launch_bounds__(512) void k_gemm2(const f16* __restrict__ Pt,
                                               const f16* __restrict__ Xt,
                                               const int* __restrict__ seg,
                                               float* __restrict__ T){
  __shared__ __align__(16) unsigned char smem[32768];
  const int b    = blockIdx.x >> 3;
  const int quad = (blockIdx.x >> 1) & 3;
  const int kc   = blockIdx.x & 1;
  const int c0   = (quad >> 1) * 128;
  const int j0   = (quad & 1) * 128;
  const int beg = seg[b], end = seg[b + 1];
  const int kbeg = beg & ~63;
  const int nst  = (end - kbeg + 63) >> 6;
  const int nst0 = (nst + 1) >> 1;
  const int st_lo = kc ? nst0 : 0;
  const int st_hi = kc ? nst  : nst0;

  const int tid = threadIdx.x;
  const int lane = tid & 63, wid = tid >> 6;
  const int wm = wid >> 2, wn = wid & 3;   // wave tile 64(c) x 32(j)
  const int r16 = lane & 15, g = lane >> 4;
  const int cr = tid >> 3, ch = tid & 7;   // staging coords (rows cr, cr+64)

  if (st_lo >= st_hi) return;              // empty chunk: T pre-zeroed

  f32x4 acc[4][2];
#pragma unroll
  for (int i = 0; i < 4; i++)
#pragma unroll
    for (int j = 0; j < 2; j++) acc[i][j] = (f32x4){0.f, 0.f, 0.f, 0.f};

  uint4 pa0, pa1, pb0, pb1;
  {
    int kk = kbeg + st_lo*64;
    pa0 = *(const uint4*)(Pt + (size_t)(c0 + cr)*EE      + kk + ch*8);
    pa1 = *(const uint4*)(Pt + (size_t)(c0 + cr + 64)*EE + kk + ch*8);
    pb0 = *(const uint4*)(Xt + (size_t)(j0 + cr)*EE      + kk + ch*8);
    pb1 = *(const uint4*)(Xt + (size_t)(j0 + cr + 64)*EE + kk + ch*8);
  }

  for (int st = st_lo; st < st_hi; st++){
    int kk = kbeg + st*64;
    if (st > st_lo) __syncthreads();
    {
      int eb = kk + ch*8;
      uint4 va0 = pa0, va1 = pa1;
      if (eb < beg || eb + 8 > end){ va0 = maskseg(va0, eb, beg, end); va1 = maskseg(va1, eb, beg, end); }
      *(uint4*)(smem + cr*128        + ((ch*16) ^ ((cr & 7) << 4))) = va0;
      *(uint4*)(smem + (cr+64)*128   + ((ch*16) ^ ((cr & 7) << 4))) = va1;
      *(uint4*)(smem + 16384 + cr*128      + ((ch*16) ^ ((cr & 7) << 4))) = pb0;
      *(uint4*)(smem + 16384 + (cr+64)*128 + ((ch*16) ^ ((cr & 7) << 4))) = pb1;
    }
    if (st + 1 < st_hi){
      int kk2 = kbeg + (st+1)*64;
      pa0 = *(const uint4*)(Pt + (size_t)(c0 + cr)*EE      + kk2 + ch*8);
      pa1 = *(const uint4*)(Pt + (size_t)(c0 + cr + 64)*EE + kk2 + ch*8);
      pb0 = *(const uint4*)(Xt + (size_t)(j0 + cr)*EE      + kk2 + ch*8);
      pb1 = *(const uint4*)(Xt + (size_t)(j0 + cr + 64)*EE + kk2 + ch*8);
    }
    __syncthreads();
#pragma unroll
    for (int ks = 0; ks < 2; ks++){
      f16x8 af[4], bf[2];
#pragma unroll
      for (int mi = 0; mi < 4; mi++){
        int row = wm*64 + mi*16 + r16;
        af[mi] = *(const f16x8*)(smem + row*128 + ((((ks*4 + g)*16)) ^ ((row & 7) << 4)));
      }
#pragma unroll
      for (int ni = 0; ni < 2; ni++){
        int row = wn*32 + ni*16 + r16;
        bf[ni] = *(const f16x8*)(smem + 16384 + row*128 + ((((ks*4 + g)*16)) ^ ((row & 7) << 4)));
      }
#pragma unroll
      for (int mi = 0; mi < 4; mi++)
#pragma unroll
        for (int ni = 0; ni < 2; ni++)
          acc[mi][ni] = __builtin_amdgcn_mfma_f32_16x16x32_f16(af[mi], bf[ni], acc[mi][ni], 0, 0, 0);
    }
  }

  float* Tb = T + (size_t)b*NCC*HH;
#pragma unroll
  for (int mi = 0; mi < 4; mi++)
#pragma unroll
    for (int ni = 0; ni < 2; ni++)
#pragma unroll
      for (int r = 0; r < 4; r++){
        int row = c0 + wm*64 + mi*16 + g*4 + r;   // c
        int col = j0 + wn*32 + ni*16 + r16;       // j
        atomicAdd(&Tb[row*HH + col], acc[mi][ni][r]);
      }
}

// ---------------- K5: per-head GEMM  pooled[b,(s,h),d] = (1/denom) * sum_j T[b,(s,h),j]*wv[j,h*32+d]
__global__ __launch_bounds__(256) void k_pool(const float* __restrict__ T,
                                              const float* __restrict__ wv,
                                              const float* __restrict__ denom,
                                              float* __restrict__ pooled){
  __shared__ float wvsh[256][36];   // 36 pad: rows stay 16B-aligned, banks rotate by 4/row
  __shared__ float Tsh[32][257];    // +1 pad
  const int b = blockIdx.x >> 3;
  const int h = blockIdx.x & 7;
  const int t = threadIdx.x;
  const int tr = t >> 3;          // 0..31
  const int tc = (t & 7) * 4;     // 0,4,...,28

#pragma unroll
  for (int p = 0; p < 8; p++){
    int j = tr + p*32;
    float4 wvv = *(const float4*)&wv[(size_t)j*HH + h*HDD + tc];
    *(float4*)&wvsh[j][tc] = wvv;
    float4 tv = *(const float4*)&T[((size_t)b*NCC + tr*NHD + h)*HH + tc + p*32];
    Tsh[tr][tc + p*32 + 0] = tv.x;
    Tsh[tr][tc + p*32 + 1] = tv.y;
    Tsh[tr][tc + p*32 + 2] = tv.z;
    Tsh[tr][tc + p*32 + 3] = tv.w;
  }
  __syncthreads();

  const int s = tr, d0 = tc;
  float ax = 0.f, ay = 0.f, az = 0.f, aw = 0.f;
#pragma unroll 4
  for (int j = 0; j < HH; j++){
    float tv = Tsh[s][j];
    float4 w4 = *(const float4*)&wvsh[j][d0];
    ax += tv * w4.x; ay += tv * w4.y; az += tv * w4.z; aw += tv * w4.w;
  }
  float sc = 1.0f / denom[b*NCC + s*NHD + h];
  float4 o = make_float4(ax*sc, ay*sc, az*sc, aw*sc);
  *(float4*)&pooled[(size_t)b*8192 + (size_t)(s*NHD + h)*HDD + d0] = o;
}

// ---------------- K6: h1pre[b][o] += sum over j-chunk of pooled[b][j]*w1[j][o] ----------------
__global__ __launch_bounds__(256) void k_mlp1(const float* __restrict__ pooled,
                                              const float* __restrict__ w1,
                                              float* __restrict__ h1pre){
  __shared__ float psh[8][256];
  const int b0 = (blockIdx.x >> 5) * 8;
  const int j0 = (blockIdx.x & 31) * 256;
  const int t = threadIdx.x;
  for (int idx = t; idx < 8*256; idx += 256){
    int bb = idx >> 8, jj = idx & 255;
    psh[bb][jj] = pooled[(size_t)(b0 + bb)*8192 + j0 + jj];
  }
  __syncthreads();
  float acc[8];
#pragma unroll
  for (int i = 0; i < 8; i++) acc[i] = 0.f;
  for (int jj = 0; jj < 256; jj++){
    float w = w1[(size_t)(j0 + jj)*HH + t];
#pragma unroll
    for (int bb = 0; bb < 8; bb++) acc[bb] += psh[bb][jj] * w;
  }
#pragma unroll
  for (int bb = 0; bb < 8; bb++) atomicAdd(&h1pre[(b0 + bb)*HH + t], acc[bb]);
}

// ---------------- K7: out = silu(h1pre + b1) @ w2 + b2 ----------------
__global__ __launch_bounds__(256) void k_mlp2(const float* __restrict__ h1pre,
                                              const float* __restrict__ b1,
                                              const float* __restrict__ w2,
                                              const float* __restrict__ b2,
                                              float* __restrict__ out){
  __shared__ float hsh[HH];
  const int b = blockIdx.x, t = threadIdx.x;
  float x = h1pre[b*HH + t] + b1[t];
  hsh[t] = x / (1.0f + __expf(-x));
  __syncthreads();
  float acc = b2[t];
  for (int j = 0; j < HH; j++) acc += hsh[j] * w2[j*HH + t];
  out[b*HH + t] = acc;
}

extern "C" void kernel_launch(void* const* d_in, const int* in_sizes, int n_in,
                              void* d_out, int out_size, void* d_ws, size_t ws_size,
                              hipStream_t stream) {
  const float* X     = (const float*)d_in[0];
  // d_in[1] edge_coords: provably unused (projection annihilates the coord-norm column)
  const int*   batch = (const int*)d_in[2];
  const float* seeds = (const float*)d_in[3];
  const float* wq    = (const float*)d_in[4];
  const float* wk    = (const float*)d_in[5];
  const float* wv    = (const float*)d_in[6];
  const float* w1    = (const float*)d_in[7];
  const float* b1    = (const float*)d_in[8];
  const float* w2    = (const float*)d_in[9];
  const float* b2    = (const float*)d_in[10];
  float* out = (float*)d_out;

  char* ws = (char*)d_ws;
  size_t off = 0;
  auto alloc = [&](size_t bytes) -> void* {
    void* p = ws + off;
    off = (off + bytes + 255) & ~(size_t)255;
    return p;
  };
  f16*   Xt     = (f16*)  alloc((size_t)NCC * EE * 2);   // 64 MiB
  f16*   Pt     = (f16*)  alloc((size_t)NCC * EE * 2);   // 64 MiB
  float* T      = (float*)alloc((size_t)BB * NCC * HH * 4); // 16 MiB
  float* qf     = (float*)alloc((size_t)SS * HH * 4);
  f16*   wsc    = (f16*)  alloc((size_t)NCC * HH * 2);
  int*   seg    = (int*)  alloc((size_t)(BB + 1) * 4);
  float* denom  = (float*)alloc((size_t)BB * NCC * 4);
  float* pooled = (float*)alloc((size_t)BB * 8192 * 4);
  float* h1pre  = (float*)alloc((size_t)BB * HH * 4);

  hipMemsetAsync(denom, 0, (size_t)BB * NCC * 4, stream);
  hipMemsetAsync(h1pre, 0, (size_t)BB * HH * 4, stream);
  hipMemsetAsync(T,     0, (size_t)BB * NCC * HH * 4, stream);  // split-K accumulator

  k_seg  <<<EE/256, 256, 0, stream>>>(batch, seg);
  k_qproj<<<SS,     256, 0, stream>>>(seeds, wq, qf);
  k_wsc  <<<NCC,    256, 0, stream>>>(qf, wk, wsc);
  k_xt   <<<EE/256, 256, 0, stream>>>(X, Xt);
  k_gemm1<<<EE/128, 512, 0, stream>>>(wsc, X, batch, Pt, denom);
  k_gemm2<<<BB*8,   512, 0, stream>>>(Pt, Xt, seg, T);
  k_pool <<<BB*NHD, 256, 0, stream>>>(T, wv, denom, pooled);
  k_mlp1 <<<256,    256, 0, stream>>>(pooled, w1, h1pre);
  k_mlp2 <<<BB,     256, 0, stream>>>(h1pre, b1, w2, b2, out);
}